// Round 2
// baseline (201.130 us; speedup 1.0000x reference)
//
#include <hip/hip_runtime.h>

#define NB 8
#define NS 4096
#define ND 768
#define G  3          // float4 groups per lane: 3 * 64 lanes * 4 floats = 768

typedef float4 f4;

static __device__ __forceinline__ float wred(float v) {
    v += __shfl_xor(v, 32, 64);
    v += __shfl_xor(v, 16, 64);
    v += __shfl_xor(v, 8, 64);
    v += __shfl_xor(v, 4, 64);
    v += __shfl_xor(v, 2, 64);
    v += __shfl_xor(v, 1, 64);
    return v;
}

static __device__ __forceinline__ f4 ld4(const float* __restrict__ p, int i) {
    return ((const f4*)p)[i];
}
static __device__ __forceinline__ float elem(const f4& v, int k) {
    return k == 0 ? v.x : k == 1 ? v.y : k == 2 ? v.z : v.w;
}

// Pass 1: table[b][orig_idx] = max seq position s of a panel token whose
// element_indices == orig_idx. (Reference's scatter-max over `kept` is
// equivalent since kept = cumsum-1 is strictly increasing in s over panels.)
__global__ void lp_scatter(const int* __restrict__ et, const int* __restrict__ ei,
                           int* __restrict__ table) {
    int t = blockIdx.x * blockDim.x + threadIdx.x;
    if (t >= NB * NS) return;
    if (et[t] == 1) {
        int b = t >> 12;
        atomicMax(&table[b * 64 + ei[t]], t & (NS - 1));
    }
}

__global__ __launch_bounds__(256) void lp_main(
    const int* __restrict__ et, const int* __restrict__ ei, const int* __restrict__ ppi,
    const float* __restrict__ sv,
    const float* __restrict__ temb,
    const float* __restrict__ iemb,
    const float* __restrict__ pemb,
    const float* __restrict__ sw,
    const float* __restrict__ sb,
    const float* __restrict__ lng,
    const float* __restrict__ lnb,
    const float* __restrict__ pw,
    const float* __restrict__ pb,
    const float* __restrict__ dw,
    const float* __restrict__ db,
    const float* __restrict__ cw,
    const float* __restrict__ cb,
    const int* __restrict__ table,
    float* __restrict__ out)
{
    const int lane = threadIdx.x & 63;
    const int t = blockIdx.x * 4 + (threadIdx.x >> 6);   // one wave per token
    const int b = t >> 12;
    const int type   = et[t];
    const int my_ei  = ei[t];
    const int my_ppi = ppi[t];

    // --- per-batch style projection, shared by own and parent feats ---
    const float sv0 = sv[b*4+0], sv1 = sv[b*4+1], sv2 = sv[b*4+2], sv3 = sv[b*4+3];
    f4 sproj[G];
    #pragma unroll
    for (int g = 0; g < G; ++g) {
        int i = g*64 + lane;                 // float4 index within a 768-dim row
        f4 w0 = ld4(sw, i), w1 = ld4(sw, 192 + i), w2 = ld4(sw, 384 + i), w3 = ld4(sw, 576 + i);
        f4 bb = ld4(sb, i);
        sproj[g].x = bb.x + sv0*w0.x + sv1*w1.x + sv2*w2.x + sv3*w3.x;
        sproj[g].y = bb.y + sv0*w0.y + sv1*w1.y + sv2*w2.y + sv3*w3.y;
        sproj[g].z = bb.z + sv0*w0.z + sv1*w1.z + sv2*w2.z + sv3*w3.z;
        sproj[g].w = bb.w + sv0*w0.w + sv1*w1.w + sv2*w2.w + sv3*w3.w;
    }

    float pout[8] = {0,0,0,0,0,0,0,0};
    float dout[8] = {0,0,0,0,0,0,0,0};
    float cout[4] = {0,0,0,0};

    if (type != 0) {
        // --- own feats: embedding sum + style proj + LayerNorm ---
        const float* te = temb + type * ND;
        const float* ie = iemb + my_ei * ND;
        const float* pe = pemb + my_ppi * ND;
        f4 x[G]; float s1 = 0.f;
        #pragma unroll
        for (int g = 0; g < G; ++g) {
            int i = g*64 + lane;
            f4 a = ld4(te, i), c = ld4(ie, i), d = ld4(pe, i);
            x[g].x = a.x + c.x + d.x + sproj[g].x;
            x[g].y = a.y + c.y + d.y + sproj[g].y;
            x[g].z = a.z + c.z + d.z + sproj[g].z;
            x[g].w = a.w + c.w + d.w + sproj[g].w;
            s1 += x[g].x + x[g].y + x[g].z + x[g].w;
        }
        float mu = wred(s1) * (1.f/ND);
        float s2 = 0.f;
        #pragma unroll
        for (int g = 0; g < G; ++g) {
            float dx = x[g].x-mu, dy = x[g].y-mu, dz = x[g].z-mu, dwv = x[g].w-mu;
            s2 += dx*dx + dy*dy + dz*dz + dwv*dwv;
        }
        float rs = rsqrtf(wred(s2) * (1.f/ND) + 1e-5f);
        f4 f[G];
        #pragma unroll
        for (int g = 0; g < G; ++g) {
            int i = g*64 + lane;
            f4 gg = ld4(lng, i), bb = ld4(lnb, i);
            f[g].x = (x[g].x-mu)*rs*gg.x + bb.x;
            f[g].y = (x[g].y-mu)*rs*gg.y + bb.y;
            f[g].z = (x[g].z-mu)*rs*gg.z + bb.z;
            f[g].w = (x[g].w-mu)*rs*gg.w + bb.w;
        }

        if (type == 1) {
            // --- panel head: feats @ (768x8) + bias ---
            float acc[8] = {0,0,0,0,0,0,0,0};
            #pragma unroll
            for (int g = 0; g < G; ++g) {
                int i = g*64 + lane;
                #pragma unroll
                for (int k = 0; k < 4; ++k) {
                    int d = i*4 + k;
                    f4 w0 = ld4(pw, d*2), w1 = ld4(pw, d*2 + 1);
                    float fv = elem(f[g], k);
                    acc[0] += fv*w0.x; acc[1] += fv*w0.y; acc[2] += fv*w0.z; acc[3] += fv*w0.w;
                    acc[4] += fv*w1.x; acc[5] += fv*w1.y; acc[6] += fv*w1.z; acc[7] += fv*w1.w;
                }
            }
            #pragma unroll
            for (int o = 0; o < 8; ++o) pout[o] = wred(acc[o]) + pb[o];
        } else {
            int pp = table[b*64 + my_ppi];
            if (pp >= 0) {
                // --- recompute parent panel feats (type embedding row 1) ---
                int ptok = b*NS + pp;
                int pei = ei[ptok], pppi = ppi[ptok];
                const float* ie2 = iemb + pei * ND;
                const float* pe2 = pemb + pppi * ND;
                f4 y[G]; float t1 = 0.f;
                #pragma unroll
                for (int g = 0; g < G; ++g) {
                    int i = g*64 + lane;
                    f4 a = ld4(temb + ND, i), c = ld4(ie2, i), d = ld4(pe2, i);
                    y[g].x = a.x + c.x + d.x + sproj[g].x;
                    y[g].y = a.y + c.y + d.y + sproj[g].y;
                    y[g].z = a.z + c.z + d.z + sproj[g].z;
                    y[g].w = a.w + c.w + d.w + sproj[g].w;
                    t1 += y[g].x + y[g].y + y[g].z + y[g].w;
                }
                float mu2 = wred(t1) * (1.f/ND);
                float t2 = 0.f;
                #pragma unroll
                for (int g = 0; g < G; ++g) {
                    float dx = y[g].x-mu2, dy = y[g].y-mu2, dz = y[g].z-mu2, dwv = y[g].w-mu2;
                    t2 += dx*dx + dy*dy + dz*dz + dwv*dwv;
                }
                float rs2 = rsqrtf(wred(t2) * (1.f/ND) + 1e-5f);
                f4 pf[G];
                #pragma unroll
                for (int g = 0; g < G; ++g) {
                    int i = g*64 + lane;
                    f4 gg = ld4(lng, i), bb = ld4(lnb, i);
                    pf[g].x = (y[g].x-mu2)*rs2*gg.x + bb.x;
                    pf[g].y = (y[g].y-mu2)*rs2*gg.y + bb.y;
                    pf[g].z = (y[g].z-mu2)*rs2*gg.z + bb.z;
                    pf[g].w = (y[g].w-mu2)*rs2*gg.w + bb.w;
                }

                if (type == 2) {
                    // --- dialog head: cat(f, pf) @ (1536x8) + bias ---
                    float acc[8] = {0,0,0,0,0,0,0,0};
                    #pragma unroll
                    for (int g = 0; g < G; ++g) {
                        int i = g*64 + lane;
                        #pragma unroll
                        for (int k = 0; k < 4; ++k) {
                            int d = i*4 + k;
                            f4 w0 = ld4(dw, d*2),            w1 = ld4(dw, d*2 + 1);
                            f4 u0 = ld4(dw, (ND + d)*2),     u1 = ld4(dw, (ND + d)*2 + 1);
                            float fv = elem(f[g], k), pv = elem(pf[g], k);
                            acc[0] += fv*w0.x + pv*u0.x; acc[1] += fv*w0.y + pv*u0.y;
                            acc[2] += fv*w0.z + pv*u0.z; acc[3] += fv*w0.w + pv*u0.w;
                            acc[4] += fv*w1.x + pv*u1.x; acc[5] += fv*w1.y + pv*u1.y;
                            acc[6] += fv*w1.z + pv*u1.z; acc[7] += fv*w1.w + pv*u1.w;
                        }
                    }
                    #pragma unroll
                    for (int o = 0; o < 8; ++o) dout[o] = wred(acc[o]) + db[o];
                } else {
                    // --- char head: cat(f, pf) @ (1536x4) + bias ---
                    float acc[4] = {0,0,0,0};
                    #pragma unroll
                    for (int g = 0; g < G; ++g) {
                        int i = g*64 + lane;
                        #pragma unroll
                        for (int k = 0; k < 4; ++k) {
                            int d = i*4 + k;
                            f4 w0 = ld4(cw, d);
                            f4 u0 = ld4(cw, ND + d);
                            float fv = elem(f[g], k), pv = elem(pf[g], k);
                            acc[0] += fv*w0.x + pv*u0.x; acc[1] += fv*w0.y + pv*u0.y;
                            acc[2] += fv*w0.z + pv*u0.z; acc[3] += fv*w0.w + pv*u0.w;
                        }
                    }
                    #pragma unroll
                    for (int o = 0; o < 4; ++o) cout[o] = wred(acc[o]) + cb[o];
                }
            }
        }
    }

    if (lane == 0) {
        f4* o1 = (f4*)(out + (size_t)t * 8);
        o1[0] = make_float4(pout[0], pout[1], pout[2], pout[3]);
        o1[1] = make_float4(pout[4], pout[5], pout[6], pout[7]);
        f4* o2 = (f4*)(out + (size_t)NB*NS*8 + (size_t)t * 8);
        o2[0] = make_float4(dout[0], dout[1], dout[2], dout[3]);
        o2[1] = make_float4(dout[4], dout[5], dout[6], dout[7]);
        f4* o3 = (f4*)(out + (size_t)NB*NS*16 + (size_t)t * 4);
        o3[0] = make_float4(cout[0], cout[1], cout[2], cout[3]);
    }
}

extern "C" void kernel_launch(void* const* d_in, const int* in_sizes, int n_in,
                              void* d_out, int out_size, void* d_ws, size_t ws_size,
                              hipStream_t stream) {
    const int* et  = (const int*)d_in[0];
    const int* ei  = (const int*)d_in[1];
    const int* ppi = (const int*)d_in[2];
    const float* sv   = (const float*)d_in[3];
    const float* temb = (const float*)d_in[4];
    const float* iemb = (const float*)d_in[5];
    const float* pemb = (const float*)d_in[6];
    const float* sw   = (const float*)d_in[7];
    const float* sb   = (const float*)d_in[8];
    const float* lng  = (const float*)d_in[9];
    const float* lnb  = (const float*)d_in[10];
    const float* pw   = (const float*)d_in[11];
    const float* pb   = (const float*)d_in[12];
    const float* dw   = (const float*)d_in[13];
    const float* db   = (const float*)d_in[14];
    const float* cw   = (const float*)d_in[15];
    const float* cbp  = (const float*)d_in[16];
    float* out = (float*)d_out;

    int* table = (int*)d_ws;                       // (B, 64) int32
    hipMemsetAsync(table, 0xFF, NB * 64 * sizeof(int), stream);  // all -1

    lp_scatter<<<(NB*NS)/256, 256, 0, stream>>>(et, ei, table);

    lp_main<<<(NB*NS)/4, 256, 0, stream>>>(et, ei, ppi, sv, temb, iemb, pemb,
                                           sw, sb, lng, lnb, pw, pb, dw, db,
                                           cw, cbp, table, out);
}

// Round 3
// 139.365 us; speedup vs baseline: 1.4432x; 1.4432x over previous
//
#include <hip/hip_runtime.h>

#define NB 8
#define NS 4096
#define ND 768

typedef float4 f4;

static __device__ __forceinline__ float wred(float v) {
    v += __shfl_xor(v, 32, 64);
    v += __shfl_xor(v, 16, 64);
    v += __shfl_xor(v, 8, 64);
    v += __shfl_xor(v, 4, 64);
    v += __shfl_xor(v, 2, 64);
    v += __shfl_xor(v, 1, 64);
    return v;
}

static __device__ __forceinline__ f4 ld4(const float* __restrict__ p, int i) {
    return ((const f4*)p)[i];
}

// ---------------------------------------------------------------------------
// Kernel 1 (lp_pre): blocks 0..127 = scatter-max parent table,
//                    blocks 128..129 = per-batch style projection (8 waves).
// table[b][idx] = max seq pos s of a panel token with element_indices == idx
// (reference's scatter-max over kept == scatter-max over s, kept monotone).
// ---------------------------------------------------------------------------
__global__ __launch_bounds__(256) void lp_pre(
    const int* __restrict__ et, const int* __restrict__ ei,
    const float* __restrict__ sv, const float* __restrict__ sw,
    const float* __restrict__ sb,
    int* __restrict__ table, float* __restrict__ sprj)
{
    if (blockIdx.x < 128) {
        int t = blockIdx.x * 256 + threadIdx.x;
        if (et[t] == 1) {
            int b = t >> 12;
            atomicMax(&table[b * 64 + ei[t]], t & (NS - 1));
        }
    } else {
        const int lane = threadIdx.x & 63;
        const int b = (blockIdx.x - 128) * 4 + (threadIdx.x >> 6);   // 0..7
        const float sv0 = sv[b*4+0], sv1 = sv[b*4+1], sv2 = sv[b*4+2], sv3 = sv[b*4+3];
        #pragma unroll
        for (int g = 0; g < 3; ++g) {
            int i = g*64 + lane;
            f4 w0 = ld4(sw, i), w1 = ld4(sw, 192+i), w2 = ld4(sw, 384+i), w3 = ld4(sw, 576+i);
            f4 bb = ld4(sb, i);
            f4 r;
            r.x = bb.x + sv0*w0.x + sv1*w1.x + sv2*w2.x + sv3*w3.x;
            r.y = bb.y + sv0*w0.y + sv1*w1.y + sv2*w2.y + sv3*w3.y;
            r.z = bb.z + sv0*w0.z + sv1*w1.z + sv2*w2.z + sv3*w3.z;
            r.w = bb.w + sv0*w0.w + sv1*w1.w + sv2*w2.w + sv3*w3.w;
            ((f4*)(sprj + b*ND))[i] = r;
        }
    }
}

// ---------------------------------------------------------------------------
// Kernel 2 (lp_parent): one wave per (b, slot); compute LN'd feats of the
// parent panel token (type row 1) and store 768 f32 to pfeat[b*64+slot].
// ---------------------------------------------------------------------------
__global__ __launch_bounds__(256) void lp_parent(
    const int* __restrict__ ei, const int* __restrict__ ppi,
    const float* __restrict__ temb, const float* __restrict__ iemb,
    const float* __restrict__ pemb, const float* __restrict__ lng,
    const float* __restrict__ lnb,
    const int* __restrict__ table, const float* __restrict__ sprj,
    float* __restrict__ pfeat)
{
    const int lane = threadIdx.x & 63;
    const int slot = blockIdx.x * 4 + (threadIdx.x >> 6);   // 0..511
    const int b = slot >> 6;
    const int pp = table[slot];
    if (pp < 0) return;                                     // wave-uniform
    const int ptok = b * NS + pp;
    const int pei = ei[ptok], pppi = ppi[ptok];
    const float* ie = iemb + pei * ND;
    const float* pe = pemb + pppi * ND;
    const float* sp = sprj + b * ND;

    f4 x[3]; float s1 = 0.f;
    #pragma unroll
    for (int g = 0; g < 3; ++g) {
        int i = g*64 + lane;
        f4 a = ld4(temb + ND, i), c = ld4(ie, i), d = ld4(pe, i), s = ld4(sp, i);
        x[g].x = a.x + c.x + d.x + s.x;
        x[g].y = a.y + c.y + d.y + s.y;
        x[g].z = a.z + c.z + d.z + s.z;
        x[g].w = a.w + c.w + d.w + s.w;
        s1 += x[g].x + x[g].y + x[g].z + x[g].w;
    }
    float mu = wred(s1) * (1.f/ND);
    float s2 = 0.f;
    #pragma unroll
    for (int g = 0; g < 3; ++g) {
        float dx = x[g].x-mu, dy = x[g].y-mu, dz = x[g].z-mu, dw_ = x[g].w-mu;
        s2 += dx*dx + dy*dy + dz*dz + dw_*dw_;
    }
    float rs = rsqrtf(wred(s2) * (1.f/ND) + 1e-5f);
    float* dst = pfeat + (size_t)slot * ND;
    #pragma unroll
    for (int g = 0; g < 3; ++g) {
        int i = g*64 + lane;
        f4 gg = ld4(lng, i), bb = ld4(lnb, i);
        f4 r;
        r.x = (x[g].x-mu)*rs*gg.x + bb.x;
        r.y = (x[g].y-mu)*rs*gg.y + bb.y;
        r.z = (x[g].z-mu)*rs*gg.z + bb.z;
        r.w = (x[g].w-mu)*rs*gg.w + bb.w;
        ((f4*)dst)[i] = r;
    }
}

// ---------------------------------------------------------------------------
// Kernel 3 (lp_main): one wave per token. Feats built in registers, written
// to a per-wave LDS region; head matmuls use an output-split lane layout so
// weight loads are fully coalesced (w[s*64+lane]) and feature values are
// broadcast from LDS (same-address reads = conflict-free).
// ---------------------------------------------------------------------------
__global__ __launch_bounds__(256) void lp_main(
    const int* __restrict__ et, const int* __restrict__ ei, const int* __restrict__ ppi,
    const float* __restrict__ temb, const float* __restrict__ iemb,
    const float* __restrict__ pemb, const float* __restrict__ lng,
    const float* __restrict__ lnb,
    const float* __restrict__ pw, const float* __restrict__ pb,
    const float* __restrict__ dw, const float* __restrict__ db,
    const float* __restrict__ cw, const float* __restrict__ cb,
    const int* __restrict__ table, const float* __restrict__ sprj,
    const float* __restrict__ pfeat,
    float* __restrict__ out)
{
    __shared__ float lds[4][2*ND];          // per-wave cat(feats, parent_feats)
    const int lane = threadIdx.x & 63;
    const int widx = threadIdx.x >> 6;
    const int t = blockIdx.x * 4 + widx;    // one wave per token
    const int b = t >> 12;
    const int type = et[t];

    float pval = 0.f, dval = 0.f, cval = 0.f;

    if (type != 0) {
        const int my_ei = ei[t], my_ppi = ppi[t];
        float* fl = lds[widx];
        const float* te = temb + type * ND;
        const float* ie = iemb + my_ei * ND;
        const float* pe = pemb + my_ppi * ND;
        const float* sp = sprj + b * ND;

        // --- own feats: embedding sum + style proj + LayerNorm ---
        f4 x[3]; float s1 = 0.f;
        #pragma unroll
        for (int g = 0; g < 3; ++g) {
            int i = g*64 + lane;
            f4 a = ld4(te, i), c = ld4(ie, i), d = ld4(pe, i), s = ld4(sp, i);
            x[g].x = a.x + c.x + d.x + s.x;
            x[g].y = a.y + c.y + d.y + s.y;
            x[g].z = a.z + c.z + d.z + s.z;
            x[g].w = a.w + c.w + d.w + s.w;
            s1 += x[g].x + x[g].y + x[g].z + x[g].w;
        }
        float mu = wred(s1) * (1.f/ND);
        float s2 = 0.f;
        #pragma unroll
        for (int g = 0; g < 3; ++g) {
            float dx = x[g].x-mu, dy = x[g].y-mu, dz = x[g].z-mu, dw_ = x[g].w-mu;
            s2 += dx*dx + dy*dy + dz*dz + dw_*dw_;
        }
        float rs = rsqrtf(wred(s2) * (1.f/ND) + 1e-5f);
        #pragma unroll
        for (int g = 0; g < 3; ++g) {
            int i = g*64 + lane;
            f4 gg = ld4(lng, i), bb = ld4(lnb, i);
            f4 r;
            r.x = (x[g].x-mu)*rs*gg.x + bb.x;
            r.y = (x[g].y-mu)*rs*gg.y + bb.y;
            r.z = (x[g].z-mu)*rs*gg.z + bb.z;
            r.w = (x[g].w-mu)*rs*gg.w + bb.w;
            ((f4*)fl)[i] = r;                   // wave-local LDS, in-order pipe
        }

        if (type == 1) {
            // panel head: o = lane&7, d = s*8 + (lane>>3); pw idx = s*64+lane
            const int di = lane >> 3;
            float acc = 0.f;
            #pragma unroll 16
            for (int s = 0; s < 96; ++s)
                acc += pw[s*64 + lane] * fl[s*8 + di];
            acc += __shfl_xor(acc, 8, 64);
            acc += __shfl_xor(acc, 16, 64);
            acc += __shfl_xor(acc, 32, 64);
            pval = acc + pb[lane & 7];
        } else {
            const int pp = table[b*64 + my_ppi];
            if (pp >= 0) {
                // parent feats: precomputed, 3 coalesced f4 loads
                const float* pfr = pfeat + (size_t)(b*64 + my_ppi) * ND;
                #pragma unroll
                for (int g = 0; g < 3; ++g)
                    ((f4*)(fl + ND))[g*64 + lane] = ld4(pfr, g*64 + lane);

                if (type == 2) {
                    const int di = lane >> 3;
                    float acc = 0.f;
                    #pragma unroll 16
                    for (int s = 0; s < 192; ++s)
                        acc += dw[s*64 + lane] * fl[s*8 + di];
                    acc += __shfl_xor(acc, 8, 64);
                    acc += __shfl_xor(acc, 16, 64);
                    acc += __shfl_xor(acc, 32, 64);
                    dval = acc + db[lane & 7];
                } else {
                    const int di = lane >> 2;
                    float acc = 0.f;
                    #pragma unroll 16
                    for (int s = 0; s < 96; ++s)
                        acc += cw[s*64 + lane] * fl[s*16 + di];
                    acc += __shfl_xor(acc, 4, 64);
                    acc += __shfl_xor(acc, 8, 64);
                    acc += __shfl_xor(acc, 16, 64);
                    acc += __shfl_xor(acc, 32, 64);
                    cval = acc + cb[lane & 3];
                }
            }
        }
    }

    // every wave writes its 20 outputs (zeros for masked / type-0 tokens)
    if (lane < 8) out[(size_t)t*8 + lane] = pval;
    if (lane < 8) out[(size_t)NB*NS*8 + (size_t)t*8 + lane] = dval;
    if (lane < 4) out[(size_t)NB*NS*16 + (size_t)t*4 + lane] = cval;
}

extern "C" void kernel_launch(void* const* d_in, const int* in_sizes, int n_in,
                              void* d_out, int out_size, void* d_ws, size_t ws_size,
                              hipStream_t stream) {
    const int* et  = (const int*)d_in[0];
    const int* ei  = (const int*)d_in[1];
    const int* ppi = (const int*)d_in[2];
    const float* sv   = (const float*)d_in[3];
    const float* temb = (const float*)d_in[4];
    const float* iemb = (const float*)d_in[5];
    const float* pemb = (const float*)d_in[6];
    const float* sw   = (const float*)d_in[7];
    const float* sb   = (const float*)d_in[8];
    const float* lng  = (const float*)d_in[9];
    const float* lnb  = (const float*)d_in[10];
    const float* pw   = (const float*)d_in[11];
    const float* pb   = (const float*)d_in[12];
    const float* dw   = (const float*)d_in[13];
    const float* db   = (const float*)d_in[14];
    const float* cw   = (const float*)d_in[15];
    const float* cbp  = (const float*)d_in[16];
    float* out = (float*)d_out;

    // ws layout: [0,2KB) table (B*64 int) | [4KB,28KB) sproj (8x768 f32)
    //            [32KB, 32KB+1.5MB) pfeat (512x768 f32)
    int*   table = (int*)d_ws;
    float* sprj  = (float*)((char*)d_ws + 4096);
    float* pfeat = (float*)((char*)d_ws + 32768);

    hipMemsetAsync(table, 0xFF, NB * 64 * sizeof(int), stream);  // all -1

    lp_pre<<<130, 256, 0, stream>>>(et, ei, sv, sw, sb, table, sprj);
    lp_parent<<<128, 256, 0, stream>>>(ei, ppi, temb, iemb, pemb, lng, lnb,
                                       table, sprj, pfeat);
    lp_main<<<(NB*NS)/4, 256, 0, stream>>>(et, ei, ppi, temb, iemb, pemb,
                                           lng, lnb, pw, pb, dw, db, cw, cbp,
                                           table, sprj, pfeat, out);
}